// Round 8
// baseline (148.206 us; speedup 1.0000x reference)
//
#include <hip/hip_runtime.h>

// PatchMask: out[b,c,t] = x[b,c,t] * (bit(c*NP + t/PATCH) ? 0 : 1)
// Setup: ONE single-block kernel builds a 3.2 KB global bitmask (L1-resident
// during apply). Apply: grid-stride (round-3 winning shape), 8 floats/lane.
// B=128, C=128, T=5000, PATCH=25, NP=200, UNITS=25600, NMASK=2560

#define PM_B 128
#define PM_C 128
#define PM_T 5000
#define PM_PATCH 25
#define PM_NP 200                      // PM_T / PM_PATCH
#define PM_UNITS (PM_C * PM_NP)        // 25600
#define PM_NMASK 2560
#define PM_MWORDS (PM_UNITS / 32)      // 800 words = 3.2 KB
#define PM_F8_PER_ROW (PM_T / 8)       // 625
#define PM_F8_TOTAL (PM_B * PM_C * PM_F8_PER_ROW)  // 10,240,000

typedef float f32x4 __attribute__((ext_vector_type(4)));

__global__ __launch_bounds__(256) void pm_build_bits(
    const int* __restrict__ idx, unsigned* __restrict__ mbits)
{
    const unsigned tid = threadIdx.x;
    // zero 800 words (200 uint4 stores)
    uint4 z = {0u, 0u, 0u, 0u};
    for (unsigned w = tid; w < PM_MWORDS / 4; w += 256u)
        ((uint4*)mbits)[w] = z;
    __syncthreads();
    for (unsigned j = tid; j < PM_NMASK; j += 256u) {
        const unsigned u = (unsigned)idx[j];
        atomicOr(&mbits[u >> 5], 1u << (u & 31u));
    }
}

__global__ __launch_bounds__(256) void pm_apply_mask(
    const f32x4* __restrict__ x,
    const unsigned* __restrict__ mbits,
    f32x4* __restrict__ out)
{
    unsigned k = blockIdx.x * 256u + threadIdx.x;
    const unsigned stride = gridDim.x * 256u;
    for (; k < PM_F8_TOTAL; k += stride) {
        const unsigned row = k / PM_F8_PER_ROW;          // b*C + c (magic-mul)
        const unsigned t0  = (k - row * PM_F8_PER_ROW) * 8u;
        const unsigned cbase = (row & (PM_C - 1)) * PM_NP;

        // two contiguous dwordx4 loads: 32 B per lane, 2 outstanding VMEM
        f32x4 v0 = __builtin_nontemporal_load(x + 2u * k);
        f32x4 v1 = __builtin_nontemporal_load(x + 2u * k + 1u);

        const unsigned p0 = t0 / PM_PATCH;
        const unsigned p7 = (t0 + 7u) / PM_PATCH;        // 8 < 25: at most 1 boundary
        const unsigned u0 = cbase + p0;
        const float m0 = ((mbits[u0 >> 5] >> (u0 & 31u)) & 1u) ? 0.0f : 1.0f;
        if (p0 == p7) {
            v0 *= m0;
            v1 *= m0;
        } else {
            const unsigned u7 = cbase + p7;
            const float m7 = ((mbits[u7 >> 5] >> (u7 & 31u)) & 1u) ? 0.0f : 1.0f;
            const unsigned boundary = p7 * PM_PATCH;     // first t in patch p7
            v0.x *= (t0 + 0u < boundary) ? m0 : m7;
            v0.y *= (t0 + 1u < boundary) ? m0 : m7;
            v0.z *= (t0 + 2u < boundary) ? m0 : m7;
            v0.w *= (t0 + 3u < boundary) ? m0 : m7;
            v1.x *= (t0 + 4u < boundary) ? m0 : m7;
            v1.y *= (t0 + 5u < boundary) ? m0 : m7;
            v1.z *= (t0 + 6u < boundary) ? m0 : m7;
            v1.w *= (t0 + 7u < boundary) ? m0 : m7;
        }

        __builtin_nontemporal_store(v0, out + 2u * k);
        __builtin_nontemporal_store(v1, out + 2u * k + 1u);
    }
}

extern "C" void kernel_launch(void* const* d_in, const int* in_sizes, int n_in,
                              void* d_out, int out_size, void* d_ws, size_t ws_size,
                              hipStream_t stream) {
    const float* x   = (const float*)d_in[0];
    const int*   idx = (const int*)d_in[1];
    float*       out = (float*)d_out;
    unsigned*    mb  = (unsigned*)d_ws;   // 800 words = 3.2 KB scratch

    pm_build_bits<<<1, 256, 0, stream>>>(idx, mb);

    // 2048 blocks x 256 threads: winning grid-stride interleave from round 3
    pm_apply_mask<<<2048, 256, 0, stream>>>(
        (const f32x4*)x, mb, (f32x4*)out);
}

// Round 9
// 124.777 us; speedup vs baseline: 1.1878x; 1.1878x over previous
//
#include <hip/hip_runtime.h>

// PatchMask: out[b,c,t] = x[b,c,t] * um[c*NP + t/PATCH]
// Setup: ONE single-block kernel builds the 100 KiB float mask
//        (1.0 default, 0.0 at the 2560 masked units).
// Apply: EXACT round-3 winning shape — grid-stride, 16 B/lane f32x4,
//        nontemporal load+store, 2048x256.
// B=128, C=128, T=5000, PATCH=25, NP=200, UNITS=25600, NMASK=2560

#define PM_B 128
#define PM_C 128
#define PM_T 5000
#define PM_PATCH 25
#define PM_NP 200                      // PM_T / PM_PATCH
#define PM_UNITS (PM_C * PM_NP)        // 25600
#define PM_NMASK 2560
#define PM_F4_PER_ROW (PM_T / 4)       // 1250
#define PM_F4_TOTAL (PM_B * PM_C * PM_F4_PER_ROW)  // 20,480,000

typedef float f32x4 __attribute__((ext_vector_type(4)));

__global__ __launch_bounds__(1024) void pm_build_mask(
    const int* __restrict__ idx, float* __restrict__ um)
{
    const unsigned tid = threadIdx.x;
    const f32x4 one = {1.0f, 1.0f, 1.0f, 1.0f};
    for (unsigned i = tid; i < PM_UNITS / 4; i += 1024u)   // 6400 f32x4 stores
        ((f32x4*)um)[i] = one;
    __syncthreads();
    for (unsigned j = tid; j < PM_NMASK; j += 1024u)       // 2560 scatter stores
        um[idx[j]] = 0.0f;
}

__global__ __launch_bounds__(256) void pm_apply_mask(
    const f32x4* __restrict__ x,
    const float* __restrict__ um,
    f32x4* __restrict__ out)
{
    unsigned i = blockIdx.x * 256u + threadIdx.x;
    const unsigned stride = gridDim.x * 256u;
    for (; i < PM_F4_TOTAL; i += stride) {
        const unsigned row = i / PM_F4_PER_ROW;          // b*C + c  (magic-mul)
        const unsigned t0  = (i - row * PM_F4_PER_ROW) * 4u;
        const float* __restrict__ um_c = um + (row & (PM_C - 1)) * PM_NP;

        f32x4 v = __builtin_nontemporal_load(x + i);

        const unsigned p0 = t0 / PM_PATCH;
        const unsigned p3 = (t0 + 3u) / PM_PATCH;
        const float m0 = um_c[p0];
        if (p0 == p3) {
            v *= m0;
        } else {
            const float m3 = um_c[p3];
            const unsigned boundary = p3 * PM_PATCH;     // first t in patch p3
            v.x *= (t0 + 0u < boundary) ? m0 : m3;
            v.y *= (t0 + 1u < boundary) ? m0 : m3;
            v.z *= (t0 + 2u < boundary) ? m0 : m3;
            v.w *= (t0 + 3u < boundary) ? m0 : m3;
        }

        __builtin_nontemporal_store(v, out + i);
    }
}

extern "C" void kernel_launch(void* const* d_in, const int* in_sizes, int n_in,
                              void* d_out, int out_size, void* d_ws, size_t ws_size,
                              hipStream_t stream) {
    const float* x   = (const float*)d_in[0];
    const int*   idx = (const int*)d_in[1];
    float*       out = (float*)d_out;
    float*       um  = (float*)d_ws;   // 25600 floats = 100 KiB scratch

    pm_build_mask<<<1, 1024, 0, stream>>>(idx, um);

    // 2048 blocks x 256 threads: winning grid-stride interleave (round 3)
    pm_apply_mask<<<2048, 256, 0, stream>>>(
        (const f32x4*)x, um, (f32x4*)out);
}